// Round 12
// baseline (1592.302 us; speedup 1.0000x reference)
//
#include <hip/hip_runtime.h>
#include <hip/hip_bf16.h>

// ---------- types ----------
typedef __attribute__((ext_vector_type(8))) short short8;
typedef __attribute__((ext_vector_type(4))) float f32x4;

#define EMB 128
#define OUT 256
#define NRAD 6
#define NDENSE 3
#define BSH 7                 // bucket shift: 128 nodes per bucket
#define MAXBKT 512            // >= ceil(N/128)
#define HB 256                // bhist blocks

static __device__ __forceinline__ unsigned short f32_to_bf16(float f) {
    union { float f; unsigned u; } v; v.f = f;
    unsigned r = v.u + 0x7fffu + ((v.u >> 16) & 1u);   // round-nearest-even
    return (unsigned short)(r >> 16);
}
static __device__ __forceinline__ float bf16_to_f32(unsigned short h) {
    union { unsigned u; float f; } v; v.u = ((unsigned)h) << 16;
    return v.f;
}
static __device__ __forceinline__ float silu(float x) {
    return x / (1.f + __expf(-x));
}
static __device__ __forceinline__ void gload_lds16(const void* gp, void* lp) {
    __builtin_amdgcn_global_load_lds(
        (const __attribute__((address_space(1))) void*)gp,
        (__attribute__((address_space(3))) void*)lp, 16, 0, 0);
}

// ---------- K0: init (convert weights + zero out) ----------
__global__ __launch_bounds__(256) void init_kernel(
        const float* __restrict__ Wup, const float* __restrict__ Wd,
        unsigned short* __restrict__ Wbf, float* __restrict__ out, int outn) {
    int i = blockIdx.x * blockDim.x + threadIdx.x;
    int stride = gridDim.x * blockDim.x;
    for (int j = i; j < outn; j += stride) out[j] = 0.f;
    const int n1 = OUT * EMB, n2 = NDENSE * OUT * OUT;
    for (int j = i; j < n1 + n2; j += stride)
        Wbf[j] = f32_to_bf16(j < n1 ? Wup[j] : Wd[j - n1]);
}

// ---------- K1: bucket histogram, atomic-free (per-block partials) ----------
__global__ __launch_bounds__(256) void bhist_kernel(
        const int* __restrict__ src, int* __restrict__ bpart, int E, int nbkt) {
    __shared__ int h[MAXBKT];
    for (int b = threadIdx.x; b < nbkt; b += 256) h[b] = 0;
    __syncthreads();
    int stride = gridDim.x * blockDim.x;
    for (int e = blockIdx.x * blockDim.x + threadIdx.x; e < E; e += stride)
        atomicAdd(&h[src[e] >> BSH], 1);
    __syncthreads();
    int* row = bpart + (size_t)blockIdx.x * MAXBKT;
    for (int b = threadIdx.x; b < nbkt; b += 256) row[b] = h[b];
}

// ---------- K2: sum partials + scan -> bbase[nbkt+1], gcursor ----------
__global__ __launch_bounds__(512) void bscan_kernel(
        const int* __restrict__ bpart, int* __restrict__ bbase,
        int* __restrict__ gcursor, int nbkt, int E) {
    __shared__ int s[MAXBKT];
    int t = threadIdx.x;
    int v = 0;
    if (t < nbkt) {
#pragma unroll 8
        for (int k = 0; k < HB; ++k) v += bpart[(size_t)k * MAXBKT + t];
    }
    s[t] = v;
    __syncthreads();
    for (int d = 1; d < MAXBKT; d <<= 1) {
        int x = (t >= d) ? s[t - d] : 0;
        __syncthreads();
        s[t] += x;
        __syncthreads();
    }
    if (t < nbkt) {
        int ex = s[t] - v;
        bbase[t] = ex;
        gcursor[t] = ex;
    }
    if (t == 0) bbase[nbkt] = E;
}

// ---------- K3: scatter edges into bucket-grouped pairs (e, src) ----------
__global__ __launch_bounds__(256) void bscatter_kernel(
        const int* __restrict__ src, int* __restrict__ gcursor,
        int2* __restrict__ pairs, int E, int nbkt) {
    __shared__ int h[MAXBKT];
    __shared__ int base[MAXBKT];
    for (int b = threadIdx.x; b < nbkt; b += 256) h[b] = 0;
    __syncthreads();
    const int per = (E + gridDim.x - 1) / gridDim.x;
    const int e0 = blockIdx.x * per;
    const int e1 = min(e0 + per, E);
    for (int e = e0 + threadIdx.x; e < e1; e += 256)
        atomicAdd(&h[src[e] >> BSH], 1);
    __syncthreads();
    for (int b = threadIdx.x; b < nbkt; b += 256)
        base[b] = h[b] ? atomicAdd(&gcursor[b], h[b]) : 0;
    __syncthreads();
    for (int e = e0 + threadIdx.x; e < e1; e += 256) {
        int s = src[e];
        int pos = atomicAdd(&base[s >> BSH], 1);
        pairs[pos] = make_int2(e, s);
    }
}

// ---------- K4: bucket accumulate (replaces local_csr + edge gather) ----------
// One block per 128-node bucket; acc[128][128] f32 in 64KB LDS.
// Lane c owns cols {c, c+32, c+64, c+96} -> ds_add_f32 bank = c (conflict-free).
// 32 edges staged per iteration: 8 m-rows (4KB) in flight per wave.
__global__ __launch_bounds__(256) void bucket_accum_kernel(
        const float* __restrict__ m, const float* __restrict__ rbf,
        const int2* __restrict__ pairs, const int* __restrict__ bbase,
        const float* __restrict__ W_rbf, uint2* __restrict__ t_pack, int N) {
    __shared__ float acc[128 * 128];       // exactly 64 KB
    const int t = threadIdx.x;
    const int b = blockIdx.x;
    const int n0 = b << BSH;
    const int nn = min(128, N - n0);
    const int p0 = bbase[b], p1 = bbase[b + 1];
    const int c  = t & 31;                 // column lane (cols c+32k)
    const int g8 = t >> 5;                 // edge slot 0..7

    for (int i = t; i < 128 * 128; i += 256) acc[i] = 0.f;

    float wk[4][6];
#pragma unroll
    for (int k = 0; k < 4; ++k)
#pragma unroll
        for (int j = 0; j < 6; ++j) wk[k][j] = W_rbf[(c + 32 * k) * NRAD + j];
    __syncthreads();

    for (int i = p0; i < p1; i += 32) {
        int2 pr[4]; float2 r[4][3]; float mv[4][4]; bool val[4];
#pragma unroll
        for (int u = 0; u < 4; ++u) {
            int idx = i + u * 8 + g8;
            val[u] = idx < p1;
            int2 p = val[u] ? pairs[idx] : make_int2(0, n0);
            pr[u] = p;
            const float2* rp = (const float2*)(rbf + (size_t)p.x * NRAD);
            r[u][0] = rp[0]; r[u][1] = rp[1]; r[u][2] = rp[2];
            const float* mrow = m + (size_t)p.x * EMB;
#pragma unroll
            for (int k = 0; k < 4; ++k) mv[u][k] = mrow[c + 32 * k];
        }
#pragma unroll
        for (int u = 0; u < 4; ++u) {
            if (!val[u]) continue;
            float* arow = acc + (pr[u].y - n0) * 128;
#pragma unroll
            for (int k = 0; k < 4; ++k) {
                float p = wk[k][0]*r[u][0].x + wk[k][1]*r[u][0].y
                        + wk[k][2]*r[u][1].x + wk[k][3]*r[u][1].y
                        + wk[k][4]*r[u][2].x + wk[k][5]*r[u][2].y;
                atomicAdd(&arow[c + 32 * k], mv[u][k] * p);
            }
        }
    }
    __syncthreads();

    // write t rows (bf16 packed, row-major [node][128])
    for (int idx = t; idx < nn * 32; idx += 256) {
        int node = idx >> 5, cc = idx & 31;
        const float* ap = acc + node * 128 + 4 * cc;
        uint2 pk;
        pk.x = (unsigned)f32_to_bf16(ap[0]) | ((unsigned)f32_to_bf16(ap[1]) << 16);
        pk.y = (unsigned)f32_to_bf16(ap[2]) | ((unsigned)f32_to_bf16(ap[3]) << 16);
        t_pack[(size_t)(n0 + node) * 32 + cc] = pk;
    }
}

// ---------- GEMM (m97-style, IDENTICAL to R11) ----------
template<int K, int ACT>
__global__ __launch_bounds__(256) void gemm2_kernel(
        const unsigned short* __restrict__ A, const unsigned short* __restrict__ W,
        const float* __restrict__ bias, unsigned short* __restrict__ C, int M) {
    __shared__ char lds[32768];
    char* As = lds;
    char* Ws = lds + 16384;

    const int w    = threadIdx.x >> 6;
    const int lane = threadIdx.x & 63;
    const int r    = lane & 15;
    const int g    = lane >> 4;
    const int wr   = w >> 1;
    const int wc   = w & 1;
    const int row0 = blockIdx.x * 128;
    const int col0 = blockIdx.y * 128;

    f32x4 acc[4][4];
#pragma unroll
    for (int i = 0; i < 4; ++i)
#pragma unroll
        for (int j = 0; j < 4; ++j) acc[i][j] = (f32x4){0.f, 0.f, 0.f, 0.f};

    const int lrow = (lane >> 3);
    const int cdst = (lane & 7) * 16;

    for (int kc = 0; kc < K; kc += 64) {
        if (kc) __syncthreads();
#pragma unroll
        for (int it = 0; it < 4; ++it) {
            int slot = it * 4 + w;
            int row  = slot * 8 + lrow;
            int csrc = cdst ^ ((row & 7) << 4);
            int ga   = row0 + row; if (ga >= M) ga = M - 1;
            gload_lds16((const char*)A + ((size_t)ga * K + kc) * 2 + csrc,
                        As + slot * 1024);
            int gw_  = col0 + row;
            gload_lds16((const char*)W + ((size_t)gw_ * K + kc) * 2 + csrc,
                        Ws + slot * 1024);
        }
        asm volatile("s_waitcnt vmcnt(0)" ::: "memory");
        __syncthreads();

#pragma unroll
        for (int ks = 0; ks < 2; ++ks) {
            short8 af[4], bf[4];
#pragma unroll
            for (int mi = 0; mi < 4; ++mi) {
                int row = wr * 64 + mi * 16 + r;
                int byte = row * 128 + ks * 64 + g * 16;
                byte ^= (r & 7) << 4;
                af[mi] = *(const short8*)(As + byte);
            }
#pragma unroll
            for (int nj = 0; nj < 4; ++nj) {
                int col = wc * 64 + nj * 16 + r;
                int byte = col * 128 + ks * 64 + g * 16;
                byte ^= (r & 7) << 4;
                bf[nj] = *(const short8*)(Ws + byte);
            }
#pragma unroll
            for (int mi = 0; mi < 4; ++mi)
#pragma unroll
                for (int nj = 0; nj < 4; ++nj)
                    acc[mi][nj] = __builtin_amdgcn_mfma_f32_16x16x32_bf16(
                        af[mi], bf[nj], acc[mi][nj], 0, 0, 0);
        }
    }

#pragma unroll
    for (int nj = 0; nj < 4; ++nj) {
        int gcol = col0 + wc * 64 + nj * 16 + r;
        float b = bias ? bias[gcol] : 0.f;
#pragma unroll
        for (int mi = 0; mi < 4; ++mi) {
#pragma unroll
            for (int q = 0; q < 4; ++q) {
                int grow = row0 + wr * 64 + mi * 16 + g * 4 + q;
                if (grow < M) {
                    float x = acc[mi][nj][q] + b;
                    if (ACT) x = silu(x);
                    C[(size_t)grow * OUT + gcol] = f32_to_bf16(x);
                }
            }
        }
    }
}

// ---------- per-graph sum: 4 partials, atomicAdd into out (IDENTICAL to R11) ----------
__global__ __launch_bounds__(256) void graph_partial_kernel(
        const unsigned short* __restrict__ h, const int* __restrict__ gids,
        float* __restrict__ out, int M) {
    int gph = blockIdx.x, s = blockIdx.y;
    int c = threadIdx.x;
    int lo = 0, hi = M;
    while (lo < hi) { int mid = (lo + hi) >> 1; if (gids[mid] < gph) lo = mid + 1; else hi = mid; }
    int lo2 = lo, hi2 = M;
    while (lo2 < hi2) { int mid = (lo2 + hi2) >> 1; if (gids[mid] < gph + 1) lo2 = mid + 1; else hi2 = mid; }
    int len = lo2 - lo;
    int q = (len + 3) >> 2;
    int b0 = lo + s * q;
    int b1 = b0 + q; if (b1 > lo2) b1 = lo2;
    float a0 = 0.f, a1 = 0.f;
    int n = b0;
    for (; n + 1 < b1; n += 2) {
        a0 += bf16_to_f32(h[(size_t)n * OUT + c]);
        a1 += bf16_to_f32(h[(size_t)(n + 1) * OUT + c]);
    }
    for (; n < b1; ++n) a0 += bf16_to_f32(h[(size_t)n * OUT + c]);
    float v = a0 + a1;
    if (b0 < b1) atomicAdd(&out[(size_t)gph * OUT + c], v);
}

// ---------- host ----------
extern "C" void kernel_launch(void* const* d_in, const int* in_sizes, int n_in,
                              void* d_out, int out_size, void* d_ws, size_t ws_size,
                              hipStream_t stream) {
    const float* m         = (const float*)d_in[0];
    const float* rbf       = (const float*)d_in[1];
    const int*   src       = (const int*)d_in[2];
    const int*   gids      = (const int*)d_in[3];
    const float* W_rbf     = (const float*)d_in[4];
    const float* W_up      = (const float*)d_in[5];
    const float* W_dense   = (const float*)d_in[6];
    const float* b_dense   = (const float*)d_in[7];
    float* out = (float*)d_out;

    const int E = in_sizes[2];
    const int N = in_sizes[3];
    const int G = out_size / OUT;
    const int nbkt = (N + 127) >> BSH;     // 391 for N=50000

    size_t off = 0;
    auto alloc = [&](size_t bytes) -> void* {
        void* p = (char*)d_ws + off;
        off += (bytes + 255) & ~(size_t)255;
        return p;
    };
    int* bpart   = (int*)alloc((size_t)HB * MAXBKT * 4);
    int* bbase   = (int*)alloc((size_t)(MAXBKT + 1) * 4);
    int* gcursor = (int*)alloc((size_t)MAXBKT * 4);
    int2* pairs  = (int2*)alloc((size_t)E * 8);
    unsigned short* t_bf = (unsigned short*)alloc((size_t)N * EMB * 2);
    unsigned short* h0   = (unsigned short*)alloc((size_t)N * OUT * 2);
    unsigned short* h1   = (unsigned short*)alloc((size_t)N * OUT * 2);
    unsigned short* Wbf  = (unsigned short*)alloc((size_t)(OUT * EMB + NDENSE * OUT * OUT) * 2);
    unsigned short* Wup_bf = Wbf;
    unsigned short* Wd_bf  = Wbf + OUT * EMB;

    // K1: bucket histogram (no deps)
    bhist_kernel<<<HB, 256, 0, stream>>>(src, bpart, E, nbkt);
    // K0: init (weights + out zero) — independent
    init_kernel<<<512, 256, 0, stream>>>(W_up, W_dense, Wbf, out, out_size);
    // K2, K3: scan + scatter
    bscan_kernel<<<1, MAXBKT, 0, stream>>>(bpart, bbase, gcursor, nbkt, E);
    bscatter_kernel<<<512, 256, 0, stream>>>(src, gcursor, pairs, E, nbkt);

    // K4: bucket accumulate (edge transform + node reduce, LDS f32)
    bucket_accum_kernel<<<nbkt, 256, 0, stream>>>(m, rbf, pairs, bbase, W_rbf,
                                                  (uint2*)t_bf, N);

    // MLP as 4 GEMMs
    dim3 ggrid((N + 127) / 128, 2);
    gemm2_kernel<EMB, 0><<<ggrid, 256, 0, stream>>>(t_bf, Wup_bf, nullptr, h0, N);
    gemm2_kernel<OUT, 1><<<ggrid, 256, 0, stream>>>(h0, Wd_bf + 0 * OUT * OUT, b_dense + 0 * OUT, h1, N);
    gemm2_kernel<OUT, 1><<<ggrid, 256, 0, stream>>>(h1, Wd_bf + 1 * OUT * OUT, b_dense + 1 * OUT, h0, N);
    gemm2_kernel<OUT, 1><<<ggrid, 256, 0, stream>>>(h0, Wd_bf + 2 * OUT * OUT, b_dense + 2 * OUT, h1, N);

    // per-graph readout (atomic into zeroed out)
    graph_partial_kernel<<<dim3(G, 4), 256, 0, stream>>>(h1, gids, out, N);
}

// Round 13
// 506.635 us; speedup vs baseline: 3.1429x; 3.1429x over previous
//
#include <hip/hip_runtime.h>
#include <hip/hip_bf16.h>

// ---------- types ----------
typedef __attribute__((ext_vector_type(8))) short short8;
typedef __attribute__((ext_vector_type(4))) float f32x4;

#define EMB 128
#define OUT 256
#define NRAD 6
#define NDENSE 3
#define BSH 7                 // bucket shift: 128 nodes per bucket
#define MAXBKT 512            // >= ceil(N/128)
#define HB 256                // setup/hist blocks

static __device__ __forceinline__ unsigned short f32_to_bf16(float f) {
    union { float f; unsigned u; } v; v.f = f;
    unsigned r = v.u + 0x7fffu + ((v.u >> 16) & 1u);   // round-nearest-even
    return (unsigned short)(r >> 16);
}
static __device__ __forceinline__ float bf16_to_f32(unsigned short h) {
    union { unsigned u; float f; } v; v.u = ((unsigned)h) << 16;
    return v.f;
}
static __device__ __forceinline__ float silu(float x) {
    return x / (1.f + __expf(-x));
}
static __device__ __forceinline__ void gload_lds16(const void* gp, void* lp) {
    __builtin_amdgcn_global_load_lds(
        (const __attribute__((address_space(1))) void*)gp,
        (__attribute__((address_space(3))) void*)lp, 16, 0, 0);
}

// ---------- K0: setup = bucket histogram partials + weight convert + out zero ----------
__global__ __launch_bounds__(256) void setup_hist_kernel(
        const int* __restrict__ src, int* __restrict__ bpart,
        const float* __restrict__ Wup, const float* __restrict__ Wd,
        unsigned short* __restrict__ Wbf, float* __restrict__ out,
        int E, int nbkt, int outn) {
    __shared__ int h[MAXBKT];
    for (int b = threadIdx.x; b < nbkt; b += 256) h[b] = 0;
    __syncthreads();
    int gtid = blockIdx.x * blockDim.x + threadIdx.x;
    int stride = gridDim.x * blockDim.x;
    for (int e = gtid; e < E; e += stride)
        atomicAdd(&h[src[e] >> BSH], 1);
    // independent small work folded in (amortizes a launch)
    for (int j = gtid; j < outn; j += stride) out[j] = 0.f;
    const int n1 = OUT * EMB, n2 = NDENSE * OUT * OUT;
    for (int j = gtid; j < n1 + n2; j += stride)
        Wbf[j] = f32_to_bf16(j < n1 ? Wup[j] : Wd[j - n1]);
    __syncthreads();
    int* row = bpart + (size_t)blockIdx.x * MAXBKT;
    for (int b = threadIdx.x; b < nbkt; b += 256) row[b] = h[b];
}

// ---------- K1: sum partials + scan -> bbase[nbkt+1], gcursor ----------
__global__ __launch_bounds__(512) void bscan_kernel(
        const int* __restrict__ bpart, int* __restrict__ bbase,
        int* __restrict__ gcursor, int nbkt, int E) {
    __shared__ int s[MAXBKT];
    int t = threadIdx.x;
    int v = 0;
    if (t < nbkt) {
#pragma unroll 8
        for (int k = 0; k < HB; ++k) v += bpart[(size_t)k * MAXBKT + t];
    }
    s[t] = v;
    __syncthreads();
    for (int d = 1; d < MAXBKT; d <<= 1) {
        int x = (t >= d) ? s[t - d] : 0;
        __syncthreads();
        s[t] += x;
        __syncthreads();
    }
    if (t < nbkt) {
        int ex = s[t] - v;
        bbase[t] = ex;
        gcursor[t] = ex;
    }
    if (t == 0) bbase[nbkt] = E;
}

// ---------- K2: scatter edges into bucket-grouped pairs (e, src) ----------
__global__ __launch_bounds__(256) void bscatter_kernel(
        const int* __restrict__ src, int* __restrict__ gcursor,
        int2* __restrict__ pairs, int E, int nbkt) {
    __shared__ int h[MAXBKT];
    __shared__ int base[MAXBKT];
    for (int b = threadIdx.x; b < nbkt; b += 256) h[b] = 0;
    __syncthreads();
    const int per = (E + gridDim.x - 1) / gridDim.x;
    const int e0 = blockIdx.x * per;
    const int e1 = min(e0 + per, E);
    for (int e = e0 + threadIdx.x; e < e1; e += 256)
        atomicAdd(&h[src[e] >> BSH], 1);
    __syncthreads();
    for (int b = threadIdx.x; b < nbkt; b += 256)
        base[b] = h[b] ? atomicAdd(&gcursor[b], h[b]) : 0;
    __syncthreads();
    for (int e = e0 + threadIdx.x; e < e1; e += 256) {
        int s = src[e];
        int pos = atomicAdd(&base[s >> BSH], 1);
        pairs[pos] = make_int2(e, s);
    }
}

// ---------- K3: per-bucket local CSR (counting sort in LDS) ----------
__global__ __launch_bounds__(256) void local_csr_kernel(
        const int2* __restrict__ pairs, const int* __restrict__ bbase,
        int* __restrict__ offsets, int* __restrict__ perm, int N, int E, int nbkt) {
    __shared__ int cnt[128], exc[128], cur[128];
    const int b = blockIdx.x;
    const int t = threadIdx.x;
    const int n0 = b << BSH;
    const int nn = min(128, N - n0);
    const int p0 = bbase[b], p1 = bbase[b + 1];
    if (t < 128) cnt[t] = 0;
    __syncthreads();
    for (int i = p0 + t; i < p1; i += 256)
        atomicAdd(&cnt[pairs[i].y - n0], 1);
    __syncthreads();
    if (t < 128) exc[t] = cnt[t];
    __syncthreads();
    for (int d = 1; d < 128; d <<= 1) {
        int x = (t >= d && t < 128) ? exc[t - d] : 0;
        __syncthreads();
        if (t < 128) exc[t] += x;
        __syncthreads();
    }
    if (t < 128) {
        int ex = exc[t] - cnt[t];
        cur[t] = ex;
        if (t < nn) offsets[n0 + t] = p0 + ex;
    }
    if (b == 0 && t == 0) offsets[N] = E;
    __syncthreads();
    for (int i = p0 + t; i < p1; i += 256) {
        int2 pr = pairs[i];
        int pos = p0 + atomicAdd(&cur[pr.y - n0], 1);
        perm[pos] = pr.x;
    }
}

// ---------- edge transform + per-node gather-sum v3b (predicated tail) ----------
// 32 lanes per edge row; 16-edge chunks; loads guarded by half-wave-uniform
// validity so tail slots issue NO memory traffic (vs clamped duplicates).
__global__ __launch_bounds__(256) void edge_accum_kernel(
        const float* __restrict__ m, const float* __restrict__ rbf,
        const int* __restrict__ perm, const int* __restrict__ offsets,
        const float* __restrict__ W_rbf, uint2* __restrict__ t_pack, int N) {
    const int lane = threadIdx.x & 63;
    const int h = lane >> 5;
    const int c = lane & 31;
    const int gw = blockIdx.x * (blockDim.x >> 6) + (threadIdx.x >> 6);
    const int nwaves = gridDim.x * (blockDim.x >> 6);

    float wk[4][6];
#pragma unroll
    for (int k = 0; k < 4; ++k)
#pragma unroll
        for (int j = 0; j < 6; ++j) wk[k][j] = W_rbf[(4 * c + k) * NRAD + j];

    for (int node = gw; node < N; node += nwaves) {
        const int beg = offsets[node], end = offsets[node + 1];
        float a0 = 0.f, a1 = 0.f, a2 = 0.f, a3 = 0.f;
        int pe = 0;
        if (beg < end) {
            int pi = beg + (lane & 15); if (pi > end - 1) pi = end - 1;
            pe = perm[pi];
        }
        for (int cb = beg; cb < end; cb += 16) {
            int pe_next = 0;
            if (cb + 16 < end) {
                int pi = cb + 16 + (lane & 15); if (pi > end - 1) pi = end - 1;
                pe_next = perm[pi];
            }
#pragma unroll
            for (int p = 0; p < 8; ++p) {
                int e = __shfl(pe, 2 * p + h);
                float2 r0 = {0.f, 0.f}, r1 = {0.f, 0.f}, r2 = {0.f, 0.f};
                float4 mv = {0.f, 0.f, 0.f, 0.f};
                if (cb + 2 * p + h < end) {      // half-wave-uniform predicate
                    const float2* rp = (const float2*)(rbf + (size_t)e * NRAD);
                    r0 = rp[0]; r1 = rp[1]; r2 = rp[2];
                    mv = *(const float4*)(m + (size_t)e * EMB + 4 * c);
                }
                float p0 = wk[0][0]*r0.x + wk[0][1]*r0.y + wk[0][2]*r1.x
                         + wk[0][3]*r1.y + wk[0][4]*r2.x + wk[0][5]*r2.y;
                float p1 = wk[1][0]*r0.x + wk[1][1]*r0.y + wk[1][2]*r1.x
                         + wk[1][3]*r1.y + wk[1][4]*r2.x + wk[1][5]*r2.y;
                float p2 = wk[2][0]*r0.x + wk[2][1]*r0.y + wk[2][2]*r1.x
                         + wk[2][3]*r1.y + wk[2][4]*r2.x + wk[2][5]*r2.y;
                float p3 = wk[3][0]*r0.x + wk[3][1]*r0.y + wk[3][2]*r1.x
                         + wk[3][3]*r1.y + wk[3][4]*r2.x + wk[3][5]*r2.y;
                a0 = fmaf(mv.x, p0, a0);
                a1 = fmaf(mv.y, p1, a1);
                a2 = fmaf(mv.z, p2, a2);
                a3 = fmaf(mv.w, p3, a3);
            }
            pe = pe_next;
        }
        a0 += __shfl_xor(a0, 32);
        a1 += __shfl_xor(a1, 32);
        a2 += __shfl_xor(a2, 32);
        a3 += __shfl_xor(a3, 32);
        if (h == 0) {
            uint2 pk;
            pk.x = (unsigned)f32_to_bf16(a0) | ((unsigned)f32_to_bf16(a1) << 16);
            pk.y = (unsigned)f32_to_bf16(a2) | ((unsigned)f32_to_bf16(a3) << 16);
            t_pack[(size_t)node * 32 + c] = pk;
        }
    }
}

// ---------- GEMM (m97-style, IDENTICAL to R11) ----------
template<int K, int ACT>
__global__ __launch_bounds__(256) void gemm2_kernel(
        const unsigned short* __restrict__ A, const unsigned short* __restrict__ W,
        const float* __restrict__ bias, unsigned short* __restrict__ C, int M) {
    __shared__ char lds[32768];
    char* As = lds;
    char* Ws = lds + 16384;

    const int w    = threadIdx.x >> 6;
    const int lane = threadIdx.x & 63;
    const int r    = lane & 15;
    const int g    = lane >> 4;
    const int wr   = w >> 1;
    const int wc   = w & 1;
    const int row0 = blockIdx.x * 128;
    const int col0 = blockIdx.y * 128;

    f32x4 acc[4][4];
#pragma unroll
    for (int i = 0; i < 4; ++i)
#pragma unroll
        for (int j = 0; j < 4; ++j) acc[i][j] = (f32x4){0.f, 0.f, 0.f, 0.f};

    const int lrow = (lane >> 3);
    const int cdst = (lane & 7) * 16;

    for (int kc = 0; kc < K; kc += 64) {
        if (kc) __syncthreads();
#pragma unroll
        for (int it = 0; it < 4; ++it) {
            int slot = it * 4 + w;
            int row  = slot * 8 + lrow;
            int csrc = cdst ^ ((row & 7) << 4);
            int ga   = row0 + row; if (ga >= M) ga = M - 1;
            gload_lds16((const char*)A + ((size_t)ga * K + kc) * 2 + csrc,
                        As + slot * 1024);
            int gw_  = col0 + row;
            gload_lds16((const char*)W + ((size_t)gw_ * K + kc) * 2 + csrc,
                        Ws + slot * 1024);
        }
        asm volatile("s_waitcnt vmcnt(0)" ::: "memory");
        __syncthreads();

#pragma unroll
        for (int ks = 0; ks < 2; ++ks) {
            short8 af[4], bf[4];
#pragma unroll
            for (int mi = 0; mi < 4; ++mi) {
                int row = wr * 64 + mi * 16 + r;
                int byte = row * 128 + ks * 64 + g * 16;
                byte ^= (r & 7) << 4;
                af[mi] = *(const short8*)(As + byte);
            }
#pragma unroll
            for (int nj = 0; nj < 4; ++nj) {
                int col = wc * 64 + nj * 16 + r;
                int byte = col * 128 + ks * 64 + g * 16;
                byte ^= (r & 7) << 4;
                bf[nj] = *(const short8*)(Ws + byte);
            }
#pragma unroll
            for (int mi = 0; mi < 4; ++mi)
#pragma unroll
                for (int nj = 0; nj < 4; ++nj)
                    acc[mi][nj] = __builtin_amdgcn_mfma_f32_16x16x32_bf16(
                        af[mi], bf[nj], acc[mi][nj], 0, 0, 0);
        }
    }

#pragma unroll
    for (int nj = 0; nj < 4; ++nj) {
        int gcol = col0 + wc * 64 + nj * 16 + r;
        float b = bias ? bias[gcol] : 0.f;
#pragma unroll
        for (int mi = 0; mi < 4; ++mi) {
#pragma unroll
            for (int q = 0; q < 4; ++q) {
                int grow = row0 + wr * 64 + mi * 16 + g * 4 + q;
                if (grow < M) {
                    float x = acc[mi][nj][q] + b;
                    if (ACT) x = silu(x);
                    C[(size_t)grow * OUT + gcol] = f32_to_bf16(x);
                }
            }
        }
    }
}

// ---------- per-graph sum: 4 partials, atomicAdd into out ----------
__global__ __launch_bounds__(256) void graph_partial_kernel(
        const unsigned short* __restrict__ h, const int* __restrict__ gids,
        float* __restrict__ out, int M) {
    int gph = blockIdx.x, s = blockIdx.y;
    int c = threadIdx.x;
    int lo = 0, hi = M;
    while (lo < hi) { int mid = (lo + hi) >> 1; if (gids[mid] < gph) lo = mid + 1; else hi = mid; }
    int lo2 = lo, hi2 = M;
    while (lo2 < hi2) { int mid = (lo2 + hi2) >> 1; if (gids[mid] < gph + 1) lo2 = mid + 1; else hi2 = mid; }
    int len = lo2 - lo;
    int q = (len + 3) >> 2;
    int b0 = lo + s * q;
    int b1 = b0 + q; if (b1 > lo2) b1 = lo2;
    float a0 = 0.f, a1 = 0.f;
    int n = b0;
    for (; n + 1 < b1; n += 2) {
        a0 += bf16_to_f32(h[(size_t)n * OUT + c]);
        a1 += bf16_to_f32(h[(size_t)(n + 1) * OUT + c]);
    }
    for (; n < b1; ++n) a0 += bf16_to_f32(h[(size_t)n * OUT + c]);
    float v = a0 + a1;
    if (b0 < b1) atomicAdd(&out[(size_t)gph * OUT + c], v);
}

// ---------- host ----------
extern "C" void kernel_launch(void* const* d_in, const int* in_sizes, int n_in,
                              void* d_out, int out_size, void* d_ws, size_t ws_size,
                              hipStream_t stream) {
    const float* m         = (const float*)d_in[0];
    const float* rbf       = (const float*)d_in[1];
    const int*   src       = (const int*)d_in[2];
    const int*   gids      = (const int*)d_in[3];
    const float* W_rbf     = (const float*)d_in[4];
    const float* W_up      = (const float*)d_in[5];
    const float* W_dense   = (const float*)d_in[6];
    const float* b_dense   = (const float*)d_in[7];
    float* out = (float*)d_out;

    const int E = in_sizes[2];
    const int N = in_sizes[3];
    const int G = out_size / OUT;
    const int nbkt = (N + 127) >> BSH;     // 391 for N=50000

    size_t off = 0;
    auto alloc = [&](size_t bytes) -> void* {
        void* p = (char*)d_ws + off;
        off += (bytes + 255) & ~(size_t)255;
        return p;
    };
    int* bpart   = (int*)alloc((size_t)HB * MAXBKT * 4);
    int* bbase   = (int*)alloc((size_t)(MAXBKT + 1) * 4);
    int* gcursor = (int*)alloc((size_t)MAXBKT * 4);
    int* offsets = (int*)alloc(((size_t)N + 1) * 4);
    int2* pairs  = (int2*)alloc((size_t)E * 8);
    int* perm    = (int*)alloc((size_t)E * 4);
    unsigned short* t_bf = (unsigned short*)alloc((size_t)N * EMB * 2);
    unsigned short* h0   = (unsigned short*)alloc((size_t)N * OUT * 2);
    unsigned short* h1   = (unsigned short*)alloc((size_t)N * OUT * 2);
    unsigned short* Wbf  = (unsigned short*)alloc((size_t)(OUT * EMB + NDENSE * OUT * OUT) * 2);
    unsigned short* Wup_bf = Wbf;
    unsigned short* Wd_bf  = Wbf + OUT * EMB;

    // K0: setup = hist partials + weight convert + out zero (merged)
    setup_hist_kernel<<<HB, 256, 0, stream>>>(src, bpart, W_up, W_dense, Wbf,
                                              out, E, nbkt, out_size);
    // K1..K3: scan, scatter, local CSR
    bscan_kernel<<<1, MAXBKT, 0, stream>>>(bpart, bbase, gcursor, nbkt, E);
    bscatter_kernel<<<512, 256, 0, stream>>>(src, gcursor, pairs, E, nbkt);
    local_csr_kernel<<<nbkt, 256, 0, stream>>>(pairs, bbase, offsets, perm, N, E, nbkt);

    // edge transform + node gather v3b (predicated tail)
    edge_accum_kernel<<<2048, 256, 0, stream>>>(m, rbf, perm, offsets, W_rbf,
                                                (uint2*)t_bf, N);

    // MLP as 4 GEMMs
    dim3 ggrid((N + 127) / 128, 2);
    gemm2_kernel<EMB, 0><<<ggrid, 256, 0, stream>>>(t_bf, Wup_bf, nullptr, h0, N);
    gemm2_kernel<OUT, 1><<<ggrid, 256, 0, stream>>>(h0, Wd_bf + 0 * OUT * OUT, b_dense + 0 * OUT, h1, N);
    gemm2_kernel<OUT, 1><<<ggrid, 256, 0, stream>>>(h1, Wd_bf + 1 * OUT * OUT, b_dense + 1 * OUT, h0, N);
    gemm2_kernel<OUT, 1><<<ggrid, 256, 0, stream>>>(h0, Wd_bf + 2 * OUT * OUT, b_dense + 2 * OUT, h1, N);

    // per-graph readout (atomic into zeroed out)
    graph_partial_kernel<<<dim3(G, 4), 256, 0, stream>>>(h1, gids, out, N);
}

// Round 14
// 439.951 us; speedup vs baseline: 3.6193x; 1.1516x over previous
//
#include <hip/hip_runtime.h>
#include <hip/hip_bf16.h>

// ---------- types ----------
typedef __attribute__((ext_vector_type(8))) short short8;
typedef __attribute__((ext_vector_type(4))) float f32x4;

#define EMB 128
#define OUT 256
#define NRAD 6
#define NDENSE 3
#define BSH 7                 // bucket shift: 128 nodes per bucket
#define MAXBKT 512            // >= ceil(N/128)
#define HB 256                // bhist blocks

static __device__ __forceinline__ unsigned short f32_to_bf16(float f) {
    union { float f; unsigned u; } v; v.f = f;
    unsigned r = v.u + 0x7fffu + ((v.u >> 16) & 1u);   // round-nearest-even
    return (unsigned short)(r >> 16);
}
static __device__ __forceinline__ float bf16_to_f32(unsigned short h) {
    union { unsigned u; float f; } v; v.u = ((unsigned)h) << 16;
    return v.f;
}
static __device__ __forceinline__ float silu(float x) {
    return x / (1.f + __expf(-x));
}
static __device__ __forceinline__ void gload_lds16(const void* gp, void* lp) {
    __builtin_amdgcn_global_load_lds(
        (const __attribute__((address_space(1))) void*)gp,
        (__attribute__((address_space(3))) void*)lp, 16, 0, 0);
}

// ---------- K0: init (convert weights + zero out)  [R11 exact] ----------
__global__ __launch_bounds__(256) void init_kernel(
        const float* __restrict__ Wup, const float* __restrict__ Wd,
        unsigned short* __restrict__ Wbf, float* __restrict__ out, int outn) {
    int i = blockIdx.x * blockDim.x + threadIdx.x;
    int stride = gridDim.x * blockDim.x;
    for (int j = i; j < outn; j += stride) out[j] = 0.f;
    const int n1 = OUT * EMB, n2 = NDENSE * OUT * OUT;
    for (int j = i; j < n1 + n2; j += stride)
        Wbf[j] = f32_to_bf16(j < n1 ? Wup[j] : Wd[j - n1]);
}

// ---------- K1: bucket histogram, atomic-free partials  [R11 exact] ----------
__global__ __launch_bounds__(256) void bhist_kernel(
        const int* __restrict__ src, int* __restrict__ bpart, int E, int nbkt) {
    __shared__ int h[MAXBKT];
    for (int b = threadIdx.x; b < nbkt; b += 256) h[b] = 0;
    __syncthreads();
    int stride = gridDim.x * blockDim.x;
    for (int e = blockIdx.x * blockDim.x + threadIdx.x; e < E; e += stride)
        atomicAdd(&h[src[e] >> BSH], 1);
    __syncthreads();
    int* row = bpart + (size_t)blockIdx.x * MAXBKT;
    for (int b = threadIdx.x; b < nbkt; b += 256) row[b] = h[b];
}

// ---------- K2: sum partials + scan ----------
__global__ __launch_bounds__(512) void bscan_kernel(
        const int* __restrict__ bpart, int* __restrict__ bbase,
        int* __restrict__ gcursor, int nbkt, int E) {
    __shared__ int s[MAXBKT];
    int t = threadIdx.x;
    int v = 0;
    if (t < nbkt) {
#pragma unroll 8
        for (int k = 0; k < HB; ++k) v += bpart[(size_t)k * MAXBKT + t];
    }
    s[t] = v;
    __syncthreads();
    for (int d = 1; d < MAXBKT; d <<= 1) {
        int x = (t >= d) ? s[t - d] : 0;
        __syncthreads();
        s[t] += x;
        __syncthreads();
    }
    if (t < nbkt) {
        int ex = s[t] - v;
        bbase[t] = ex;
        gcursor[t] = ex;
    }
    if (t == 0) bbase[nbkt] = E;
}

// ---------- K3: scatter edges into bucket-grouped pairs  [R11 exact] ----------
__global__ __launch_bounds__(256) void bscatter_kernel(
        const int* __restrict__ src, int* __restrict__ gcursor,
        int2* __restrict__ pairs, int E, int nbkt) {
    __shared__ int h[MAXBKT];
    __shared__ int base[MAXBKT];
    for (int b = threadIdx.x; b < nbkt; b += 256) h[b] = 0;
    __syncthreads();
    const int per = (E + gridDim.x - 1) / gridDim.x;
    const int e0 = blockIdx.x * per;
    const int e1 = min(e0 + per, E);
    for (int e = e0 + threadIdx.x; e < e1; e += 256)
        atomicAdd(&h[src[e] >> BSH], 1);
    __syncthreads();
    for (int b = threadIdx.x; b < nbkt; b += 256)
        base[b] = h[b] ? atomicAdd(&gcursor[b], h[b]) : 0;
    __syncthreads();
    for (int e = e0 + threadIdx.x; e < e1; e += 256) {
        int s = src[e];
        int pos = atomicAdd(&base[s >> BSH], 1);
        pairs[pos] = make_int2(e, s);
    }
}

// ---------- K4: per-bucket local CSR  [R11 exact] ----------
__global__ __launch_bounds__(256) void local_csr_kernel(
        const int2* __restrict__ pairs, const int* __restrict__ bbase,
        int* __restrict__ offsets, int* __restrict__ perm, int N, int E, int nbkt) {
    __shared__ int cnt[128], exc[128], cur[128];
    const int b = blockIdx.x;
    const int t = threadIdx.x;
    const int n0 = b << BSH;
    const int nn = min(128, N - n0);
    const int p0 = bbase[b], p1 = bbase[b + 1];
    if (t < 128) cnt[t] = 0;
    __syncthreads();
    for (int i = p0 + t; i < p1; i += 256)
        atomicAdd(&cnt[pairs[i].y - n0], 1);
    __syncthreads();
    if (t < 128) exc[t] = cnt[t];
    __syncthreads();
    for (int d = 1; d < 128; d <<= 1) {
        int x = (t >= d && t < 128) ? exc[t - d] : 0;
        __syncthreads();
        if (t < 128) exc[t] += x;
        __syncthreads();
    }
    if (t < 128) {
        int ex = exc[t] - cnt[t];
        cur[t] = ex;
        if (t < nn) offsets[n0 + t] = p0 + ex;
    }
    if (b == 0 && t == 0) offsets[N] = E;
    __syncthreads();
    for (int i = p0 + t; i < p1; i += 256) {
        int2 pr = pairs[i];
        int pos = p0 + atomicAdd(&cur[pr.y - n0], 1);
        perm[pos] = pr.x;
    }
}

// ---------- edge transform + per-node gather-sum v3  [R11 exact, unpredicated] ----------
__global__ __launch_bounds__(256) void edge_accum_kernel(
        const float* __restrict__ m, const float* __restrict__ rbf,
        const int* __restrict__ perm, const int* __restrict__ offsets,
        const float* __restrict__ W_rbf, uint2* __restrict__ t_pack, int N) {
    const int lane = threadIdx.x & 63;
    const int h = lane >> 5;
    const int c = lane & 31;
    const int gw = blockIdx.x * (blockDim.x >> 6) + (threadIdx.x >> 6);
    const int nwaves = gridDim.x * (blockDim.x >> 6);

    float wk[4][6];
#pragma unroll
    for (int k = 0; k < 4; ++k)
#pragma unroll
        for (int j = 0; j < 6; ++j) wk[k][j] = W_rbf[(4 * c + k) * NRAD + j];

    for (int node = gw; node < N; node += nwaves) {
        const int beg = offsets[node], end = offsets[node + 1];
        float a0 = 0.f, a1 = 0.f, a2 = 0.f, a3 = 0.f;
        int pe = 0;
        if (beg < end) {
            int pi = beg + (lane & 15); if (pi > end - 1) pi = end - 1;
            pe = perm[pi];
        }
        for (int cb = beg; cb < end; cb += 16) {
            int pe_next = 0;
            if (cb + 16 < end) {
                int pi = cb + 16 + (lane & 15); if (pi > end - 1) pi = end - 1;
                pe_next = perm[pi];
            }
#pragma unroll
            for (int p = 0; p < 8; ++p) {
                int e = __shfl(pe, 2 * p + h);
                const float2* rp = (const float2*)(rbf + (size_t)e * NRAD);
                float2 r0 = rp[0], r1 = rp[1], r2 = rp[2];
                float4 mv = *(const float4*)(m + (size_t)e * EMB + 4 * c);
                float g = (cb + 2 * p + h < end) ? 1.f : 0.f;
                float p0 = (wk[0][0]*r0.x + wk[0][1]*r0.y + wk[0][2]*r1.x
                          + wk[0][3]*r1.y + wk[0][4]*r2.x + wk[0][5]*r2.y) * g;
                float p1 = (wk[1][0]*r0.x + wk[1][1]*r0.y + wk[1][2]*r1.x
                          + wk[1][3]*r1.y + wk[1][4]*r2.x + wk[1][5]*r2.y) * g;
                float p2 = (wk[2][0]*r0.x + wk[2][1]*r0.y + wk[2][2]*r1.x
                          + wk[2][3]*r1.y + wk[2][4]*r2.x + wk[2][5]*r2.y) * g;
                float p3 = (wk[3][0]*r0.x + wk[3][1]*r0.y + wk[3][2]*r1.x
                          + wk[3][3]*r1.y + wk[3][4]*r2.x + wk[3][5]*r2.y) * g;
                a0 = fmaf(mv.x, p0, a0);
                a1 = fmaf(mv.y, p1, a1);
                a2 = fmaf(mv.z, p2, a2);
                a3 = fmaf(mv.w, p3, a3);
            }
            pe = pe_next;
        }
        a0 += __shfl_xor(a0, 32);
        a1 += __shfl_xor(a1, 32);
        a2 += __shfl_xor(a2, 32);
        a3 += __shfl_xor(a3, 32);
        if (h == 0) {
            uint2 pk;
            pk.x = (unsigned)f32_to_bf16(a0) | ((unsigned)f32_to_bf16(a1) << 16);
            pk.y = (unsigned)f32_to_bf16(a2) | ((unsigned)f32_to_bf16(a3) << 16);
            t_pack[(size_t)node * 32 + c] = pk;
        }
    }
}

// ---------- fused MLP v2: up-proj + 3x(dense+silu) in ONE kernel ----------
// 64-row block, 4 waves; wave w = all 64 rows x cols [w*64,+64), acc[4][4].
// Inter-layer activations in Abuf (64 x 512B, XOR swizzle (row&7)<<4 both sides).
// Weights staged per-64-K-chunk into Wbuf via global_load_lds (gemm2 pattern).
__global__ __launch_bounds__(256) void fused_mlp2_kernel(
        const unsigned short* __restrict__ A0,    // [M,128] bf16
        const unsigned short* __restrict__ Wup,   // [256,128] bf16
        const unsigned short* __restrict__ Wd,    // [3,256,256] bf16
        const float* __restrict__ bd,             // [3,256]
        unsigned short* __restrict__ Hout, int M) {
    __shared__ char Abuf[32768];   // layer0: 64 x 256B ; layers1-3: 64 x 512B
    __shared__ char Wbuf[32768];   // 256 out-rows x 128B (one 64-K chunk)
    const int t    = threadIdx.x;
    const int w    = t >> 6;
    const int lane = t & 63;
    const int r    = lane & 15;
    const int g    = lane >> 4;
    const int row0 = blockIdx.x * 64;

    f32x4 acc[4][4];

    // ---- stage A0: 64 rows x 256B (pre-swizzled source, linear dest) ----
#pragma unroll
    for (int it = 0; it < 4; ++it) {
        int unit = it * 256 + t;           // 0..1023
        int row  = unit >> 4;              // 0..63
        int seg  = unit & 15;
        int csrc = (seg * 16) ^ ((row & 7) << 4);
        int ga = row0 + row; if (ga >= M) ga = M - 1;
        gload_lds16((const char*)A0 + (size_t)ga * 256 + csrc, Abuf + unit * 16);
    }

    // ---- layer 0: K=128, A from Abuf(256B rows), W=Wup ----
#pragma unroll
    for (int i = 0; i < 4; ++i)
#pragma unroll
        for (int j = 0; j < 4; ++j) acc[i][j] = (f32x4){0.f, 0.f, 0.f, 0.f};
#pragma unroll
    for (int kci = 0; kci < 2; ++kci) {
        const int kc = kci * 64;
        if (kci) __syncthreads();          // prev chunk compute done
#pragma unroll
        for (int it = 0; it < 8; ++it) {
            int unit = it * 256 + t;       // 0..2047
            int wrow = unit >> 3;          // 0..255
            int seg  = unit & 7;
            int csrc = (seg * 16) ^ ((wrow & 7) << 4);
            gload_lds16((const char*)Wup + (size_t)wrow * 256 + kc * 2 + csrc,
                        Wbuf + unit * 16);
        }
        asm volatile("s_waitcnt vmcnt(0)" ::: "memory");
        __syncthreads();
#pragma unroll
        for (int ks = 0; ks < 2; ++ks) {
            short8 af[4], bf[4];
#pragma unroll
            for (int mi = 0; mi < 4; ++mi) {
                int row = mi * 16 + r;
                int off = kc * 2 + ks * 64 + g * 16;
                af[mi] = *(const short8*)(Abuf + row * 256 + (off ^ ((row & 7) << 4)));
            }
#pragma unroll
            for (int nj = 0; nj < 4; ++nj) {
                int col = w * 64 + nj * 16 + r;
                bf[nj] = *(const short8*)(Wbuf + col * 128
                          + ((ks * 64 + g * 16) ^ ((col & 7) << 4)));
            }
#pragma unroll
            for (int mi = 0; mi < 4; ++mi)
#pragma unroll
                for (int nj = 0; nj < 4; ++nj)
                    acc[mi][nj] = __builtin_amdgcn_mfma_f32_16x16x32_bf16(
                        af[mi], bf[nj], acc[mi][nj], 0, 0, 0);
        }
    }
    __syncthreads();                        // all Abuf reads done
    // write layer0 output (no bias/act) into Abuf, 512B rows
#pragma unroll
    for (int mi = 0; mi < 4; ++mi)
#pragma unroll
        for (int nj = 0; nj < 4; ++nj)
#pragma unroll
            for (int q = 0; q < 4; ++q) {
                int row = mi * 16 + g * 4 + q;
                int col = w * 64 + nj * 16 + r;
                *(unsigned short*)(Abuf + row * 512 + ((col * 2) ^ ((row & 7) << 4)))
                    = f32_to_bf16(acc[mi][nj][q]);
            }
    __syncthreads();

    // ---- layers 1..3: K=256, A from Abuf(512B rows), W=Wd[ell] ----
    for (int ell = 0; ell < NDENSE; ++ell) {
        const unsigned short* Wl = Wd + (size_t)ell * OUT * OUT;
        const float* bias = bd + ell * OUT;
#pragma unroll
        for (int i = 0; i < 4; ++i)
#pragma unroll
            for (int j = 0; j < 4; ++j) acc[i][j] = (f32x4){0.f, 0.f, 0.f, 0.f};
#pragma unroll
        for (int kci = 0; kci < 4; ++kci) {
            const int kc = kci * 64;
            __syncthreads();               // prior compute / write-back done
#pragma unroll
            for (int it = 0; it < 8; ++it) {
                int unit = it * 256 + t;
                int wrow = unit >> 3;
                int seg  = unit & 7;
                int csrc = (seg * 16) ^ ((wrow & 7) << 4);
                gload_lds16((const char*)Wl + (size_t)wrow * 512 + kc * 2 + csrc,
                            Wbuf + unit * 16);
            }
            asm volatile("s_waitcnt vmcnt(0)" ::: "memory");
            __syncthreads();
#pragma unroll
            for (int ks = 0; ks < 2; ++ks) {
                short8 af[4], bf[4];
#pragma unroll
                for (int mi = 0; mi < 4; ++mi) {
                    int row = mi * 16 + r;
                    int off = kc * 2 + ks * 64 + g * 16;
                    af[mi] = *(const short8*)(Abuf + row * 512 + (off ^ ((row & 7) << 4)));
                }
#pragma unroll
                for (int nj = 0; nj < 4; ++nj) {
                    int col = w * 64 + nj * 16 + r;
                    bf[nj] = *(const short8*)(Wbuf + col * 128
                              + ((ks * 64 + g * 16) ^ ((col & 7) << 4)));
                }
#pragma unroll
                for (int mi = 0; mi < 4; ++mi)
#pragma unroll
                    for (int nj = 0; nj < 4; ++nj)
                        acc[mi][nj] = __builtin_amdgcn_mfma_f32_16x16x32_bf16(
                            af[mi], bf[nj], acc[mi][nj], 0, 0, 0);
            }
        }
        __syncthreads();                    // all Abuf reads done
        if (ell < NDENSE - 1) {
#pragma unroll
            for (int mi = 0; mi < 4; ++mi)
#pragma unroll
                for (int nj = 0; nj < 4; ++nj) {
                    int col = w * 64 + nj * 16 + r;
                    float b = bias[col];
#pragma unroll
                    for (int q = 0; q < 4; ++q) {
                        int row = mi * 16 + g * 4 + q;
                        *(unsigned short*)(Abuf + row * 512
                            + ((col * 2) ^ ((row & 7) << 4)))
                            = f32_to_bf16(silu(acc[mi][nj][q] + b));
                    }
                }
            __syncthreads();
        } else {
            // final layer -> global
#pragma unroll
            for (int nj = 0; nj < 4; ++nj) {
                int gcol = w * 64 + nj * 16 + r;
                float b = bias[gcol];
#pragma unroll
                for (int mi = 0; mi < 4; ++mi)
#pragma unroll
                    for (int q = 0; q < 4; ++q) {
                        int grow = row0 + mi * 16 + g * 4 + q;
                        if (grow < M)
                            Hout[(size_t)grow * OUT + gcol]
                                = f32_to_bf16(silu(acc[mi][nj][q] + b));
                    }
            }
        }
    }
}

// ---------- per-graph sum: 4 partials, atomicAdd into out  [R11 exact] ----------
__global__ __launch_bounds__(256) void graph_partial_kernel(
        const unsigned short* __restrict__ h, const int* __restrict__ gids,
        float* __restrict__ out, int M) {
    int gph = blockIdx.x, s = blockIdx.y;
    int c = threadIdx.x;
    int lo = 0, hi = M;
    while (lo < hi) { int mid = (lo + hi) >> 1; if (gids[mid] < gph) lo = mid + 1; else hi = mid; }
    int lo2 = lo, hi2 = M;
    while (lo2 < hi2) { int mid = (lo2 + hi2) >> 1; if (gids[mid] < gph + 1) lo2 = mid + 1; else hi2 = mid; }
    int len = lo2 - lo;
    int q = (len + 3) >> 2;
    int b0 = lo + s * q;
    int b1 = b0 + q; if (b1 > lo2) b1 = lo2;
    float a0 = 0.f, a1 = 0.f;
    int n = b0;
    for (; n + 1 < b1; n += 2) {
        a0 += bf16_to_f32(h[(size_t)n * OUT + c]);
        a1 += bf16_to_f32(h[(size_t)(n + 1) * OUT + c]);
    }
    for (; n < b1; ++n) a0 += bf16_to_f32(h[(size_t)n * OUT + c]);
    float v = a0 + a1;
    if (b0 < b1) atomicAdd(&out[(size_t)gph * OUT + c], v);
}

// ---------- host ----------
extern "C" void kernel_launch(void* const* d_in, const int* in_sizes, int n_in,
                              void* d_out, int out_size, void* d_ws, size_t ws_size,
                              hipStream_t stream) {
    const float* m         = (const float*)d_in[0];
    const float* rbf       = (const float*)d_in[1];
    const int*   src       = (const int*)d_in[2];
    const int*   gids      = (const int*)d_in[3];
    const float* W_rbf     = (const float*)d_in[4];
    const float* W_up      = (const float*)d_in[5];
    const float* W_dense   = (const float*)d_in[6];
    const float* b_dense   = (const float*)d_in[7];
    float* out = (float*)d_out;

    const int E = in_sizes[2];
    const int N = in_sizes[3];
    const int G = out_size / OUT;
    const int nbkt = (N + 127) >> BSH;     // 391 for N=50000

    size_t off = 0;
    auto alloc = [&](size_t bytes) -> void* {
        void* p = (char*)d_ws + off;
        off += (bytes + 255) & ~(size_t)255;
        return p;
    };
    int* bpart   = (int*)alloc((size_t)HB * MAXBKT * 4);
    int* bbase   = (int*)alloc((size_t)(MAXBKT + 1) * 4);
    int* gcursor = (int*)alloc((size_t)MAXBKT * 4);
    int* offsets = (int*)alloc(((size_t)N + 1) * 4);
    int2* pairs  = (int2*)alloc((size_t)E * 8);
    int* perm    = (int*)alloc((size_t)E * 4);
    unsigned short* t_bf = (unsigned short*)alloc((size_t)N * EMB * 2);
    unsigned short* h1   = (unsigned short*)alloc((size_t)N * OUT * 2);
    unsigned short* Wbf  = (unsigned short*)alloc((size_t)(OUT * EMB + NDENSE * OUT * OUT) * 2);
    unsigned short* Wup_bf = Wbf;
    unsigned short* Wd_bf  = Wbf + OUT * EMB;

    // K1: bucket histogram (no deps)
    bhist_kernel<<<HB, 256, 0, stream>>>(src, bpart, E, nbkt);
    // K0: init (weights + out zero) — independent
    init_kernel<<<512, 256, 0, stream>>>(W_up, W_dense, Wbf, out, out_size);
    // K2..K4: scan, scatter, local CSR
    bscan_kernel<<<1, MAXBKT, 0, stream>>>(bpart, bbase, gcursor, nbkt, E);
    bscatter_kernel<<<512, 256, 0, stream>>>(src, gcursor, pairs, E, nbkt);
    local_csr_kernel<<<nbkt, 256, 0, stream>>>(pairs, bbase, offsets, perm, N, E, nbkt);

    // edge transform + node gather v3 (R11 exact)
    edge_accum_kernel<<<2048, 256, 0, stream>>>(m, rbf, perm, offsets, W_rbf,
                                                (uint2*)t_bf, N);

    // fused MLP: up-proj + 3x dense+silu in one kernel
    fused_mlp2_kernel<<<(N + 63) / 64, 256, 0, stream>>>(t_bf, Wup_bf, Wd_bf,
                                                         b_dense, h1, N);

    // per-graph readout (atomic into zeroed out)
    graph_partial_kernel<<<dim3(G, 4), 256, 0, stream>>>(h1, gids, out, N);
}

// Round 15
// 423.124 us; speedup vs baseline: 3.7632x; 1.0398x over previous
//
#include <hip/hip_runtime.h>
#include <hip/hip_bf16.h>

// ---------- types ----------
typedef __attribute__((ext_vector_type(8))) short short8;
typedef __attribute__((ext_vector_type(4))) float f32x4;

#define EMB 128
#define OUT 256
#define NRAD 6
#define NDENSE 3
#define BSH 7                 // bucket shift: 128 nodes per bucket
#define MAXBKT 512            // >= ceil(N/128)
#define HB 256                // setup/hist blocks

static __device__ __forceinline__ unsigned short f32_to_bf16(float f) {
    union { float f; unsigned u; } v; v.f = f;
    unsigned r = v.u + 0x7fffu + ((v.u >> 16) & 1u);   // round-nearest-even
    return (unsigned short)(r >> 16);
}
static __device__ __forceinline__ float silu(float x) {
    return x / (1.f + __expf(-x));
}
static __device__ __forceinline__ void gload_lds16(const void* gp, void* lp) {
    __builtin_amdgcn_global_load_lds(
        (const __attribute__((address_space(1))) void*)gp,
        (__attribute__((address_space(3))) void*)lp, 16, 0, 0);
}

// ---------- K0: setup = bucket hist partials + weight convert + out zero ----------
__global__ __launch_bounds__(256) void setup_hist_kernel(
        const int* __restrict__ src, int* __restrict__ bpart,
        const float* __restrict__ Wup, const float* __restrict__ Wd,
        unsigned short* __restrict__ Wbf, float* __restrict__ out,
        int E, int nbkt, int outn) {
    __shared__ int h[MAXBKT];
    for (int b = threadIdx.x; b < nbkt; b += 256) h[b] = 0;
    __syncthreads();
    int gtid = blockIdx.x * blockDim.x + threadIdx.x;
    int stride = gridDim.x * blockDim.x;
    for (int e = gtid; e < E; e += stride)
        atomicAdd(&h[src[e] >> BSH], 1);
    for (int j = gtid; j < outn; j += stride) out[j] = 0.f;
    const int n1 = OUT * EMB, n2 = NDENSE * OUT * OUT;
    for (int j = gtid; j < n1 + n2; j += stride)
        Wbf[j] = f32_to_bf16(j < n1 ? Wup[j] : Wd[j - n1]);
    __syncthreads();
    int* row = bpart + (size_t)blockIdx.x * MAXBKT;
    for (int b = threadIdx.x; b < nbkt; b += 256) row[b] = h[b];
}

// ---------- K1: sum partials + scan ----------
__global__ __launch_bounds__(512) void bscan_kernel(
        const int* __restrict__ bpart, int* __restrict__ bbase,
        int* __restrict__ gcursor, int nbkt, int E) {
    __shared__ int s[MAXBKT];
    int t = threadIdx.x;
    int v = 0;
    if (t < nbkt) {
#pragma unroll 8
        for (int k = 0; k < HB; ++k) v += bpart[(size_t)k * MAXBKT + t];
    }
    s[t] = v;
    __syncthreads();
    for (int d = 1; d < MAXBKT; d <<= 1) {
        int x = (t >= d) ? s[t - d] : 0;
        __syncthreads();
        s[t] += x;
        __syncthreads();
    }
    if (t < nbkt) {
        int ex = s[t] - v;
        bbase[t] = ex;
        gcursor[t] = ex;
    }
    if (t == 0) bbase[nbkt] = E;
}

// ---------- K2: scatter edges into bucket-grouped pairs  [R11 exact] ----------
__global__ __launch_bounds__(256) void bscatter_kernel(
        const int* __restrict__ src, int* __restrict__ gcursor,
        int2* __restrict__ pairs, int E, int nbkt) {
    __shared__ int h[MAXBKT];
    __shared__ int base[MAXBKT];
    for (int b = threadIdx.x; b < nbkt; b += 256) h[b] = 0;
    __syncthreads();
    const int per = (E + gridDim.x - 1) / gridDim.x;
    const int e0 = blockIdx.x * per;
    const int e1 = min(e0 + per, E);
    for (int e = e0 + threadIdx.x; e < e1; e += 256)
        atomicAdd(&h[src[e] >> BSH], 1);
    __syncthreads();
    for (int b = threadIdx.x; b < nbkt; b += 256)
        base[b] = h[b] ? atomicAdd(&gcursor[b], h[b]) : 0;
    __syncthreads();
    for (int e = e0 + threadIdx.x; e < e1; e += 256) {
        int s = src[e];
        int pos = atomicAdd(&base[s >> BSH], 1);
        pairs[pos] = make_int2(e, s);
    }
}

// ---------- K3: per-bucket local CSR  [R11 exact] ----------
__global__ __launch_bounds__(256) void local_csr_kernel(
        const int2* __restrict__ pairs, const int* __restrict__ bbase,
        int* __restrict__ offsets, int* __restrict__ perm, int N, int E, int nbkt) {
    __shared__ int cnt[128], exc[128], cur[128];
    const int b = blockIdx.x;
    const int t = threadIdx.x;
    const int n0 = b << BSH;
    const int nn = min(128, N - n0);
    const int p0 = bbase[b], p1 = bbase[b + 1];
    if (t < 128) cnt[t] = 0;
    __syncthreads();
    for (int i = p0 + t; i < p1; i += 256)
        atomicAdd(&cnt[pairs[i].y - n0], 1);
    __syncthreads();
    if (t < 128) exc[t] = cnt[t];
    __syncthreads();
    for (int d = 1; d < 128; d <<= 1) {
        int x = (t >= d && t < 128) ? exc[t - d] : 0;
        __syncthreads();
        if (t < 128) exc[t] += x;
        __syncthreads();
    }
    if (t < 128) {
        int ex = exc[t] - cnt[t];
        cur[t] = ex;
        if (t < nn) offsets[n0 + t] = p0 + ex;
    }
    if (b == 0 && t == 0) offsets[N] = E;
    __syncthreads();
    for (int i = p0 + t; i < p1; i += 256) {
        int2 pr = pairs[i];
        int pos = p0 + atomicAdd(&cur[pr.y - n0], 1);
        perm[pos] = pr.x;
    }
}

// ---------- edge transform + per-node gather-sum v4 (32-edge chunks) ----------
// 32 lanes per edge row; 32 perm ids staged in lane&31; 16 paired p-iterations
// -> up to 16 m-rows in flight per wave. Unpredicated loads (R13 lesson).
__global__ __launch_bounds__(256) void edge_accum_kernel(
        const float* __restrict__ m, const float* __restrict__ rbf,
        const int* __restrict__ perm, const int* __restrict__ offsets,
        const float* __restrict__ W_rbf, uint2* __restrict__ t_pack, int N) {
    const int lane = threadIdx.x & 63;
    const int h = lane >> 5;
    const int c = lane & 31;
    const int gw = blockIdx.x * (blockDim.x >> 6) + (threadIdx.x >> 6);
    const int nwaves = gridDim.x * (blockDim.x >> 6);

    float wk[4][6];
#pragma unroll
    for (int k = 0; k < 4; ++k)
#pragma unroll
        for (int j = 0; j < 6; ++j) wk[k][j] = W_rbf[(4 * c + k) * NRAD + j];

    for (int node = gw; node < N; node += nwaves) {
        const int beg = offsets[node], end = offsets[node + 1];
        float a0 = 0.f, a1 = 0.f, a2 = 0.f, a3 = 0.f;
        int pe = 0;
        if (beg < end) {
            int pi = beg + (lane & 31); if (pi > end - 1) pi = end - 1;
            pe = perm[pi];
        }
        for (int cb = beg; cb < end; cb += 32) {
            int pe_next = 0;
            if (cb + 32 < end) {
                int pi = cb + 32 + (lane & 31); if (pi > end - 1) pi = end - 1;
                pe_next = perm[pi];
            }
#pragma unroll
            for (int p = 0; p < 16; ++p) {
                int e = __shfl(pe, 2 * p + h);
                const float2* rp = (const float2*)(rbf + (size_t)e * NRAD);
                float2 r0 = rp[0], r1 = rp[1], r2 = rp[2];
                float4 mv = *(const float4*)(m + (size_t)e * EMB + 4 * c);
                float g = (cb + 2 * p + h < end) ? 1.f : 0.f;
                float p0 = (wk[0][0]*r0.x + wk[0][1]*r0.y + wk[0][2]*r1.x
                          + wk[0][3]*r1.y + wk[0][4]*r2.x + wk[0][5]*r2.y) * g;
                float p1 = (wk[1][0]*r0.x + wk[1][1]*r0.y + wk[1][2]*r1.x
                          + wk[1][3]*r1.y + wk[1][4]*r2.x + wk[1][5]*r2.y) * g;
                float p2 = (wk[2][0]*r0.x + wk[2][1]*r0.y + wk[2][2]*r1.x
                          + wk[2][3]*r1.y + wk[2][4]*r2.x + wk[2][5]*r2.y) * g;
                float p3 = (wk[3][0]*r0.x + wk[3][1]*r0.y + wk[3][2]*r1.x
                          + wk[3][3]*r1.y + wk[3][4]*r2.x + wk[3][5]*r2.y) * g;
                a0 = fmaf(mv.x, p0, a0);
                a1 = fmaf(mv.y, p1, a1);
                a2 = fmaf(mv.z, p2, a2);
                a3 = fmaf(mv.w, p3, a3);
            }
            pe = pe_next;
        }
        a0 += __shfl_xor(a0, 32);
        a1 += __shfl_xor(a1, 32);
        a2 += __shfl_xor(a2, 32);
        a3 += __shfl_xor(a3, 32);
        if (h == 0) {
            uint2 pk;
            pk.x = (unsigned)f32_to_bf16(a0) | ((unsigned)f32_to_bf16(a1) << 16);
            pk.y = (unsigned)f32_to_bf16(a2) | ((unsigned)f32_to_bf16(a3) << 16);
            t_pack[(size_t)node * 32 + c] = pk;
        }
    }
}

// ---------- fused MLP v3: up-proj + 3x(dense+silu) + per-graph reduce ----------
// R14 structure; final layer reduces rows in-register and atomicAdds into out.
__global__ __launch_bounds__(256) void fused_mlp2_kernel(
        const unsigned short* __restrict__ A0,    // [M,128] bf16
        const unsigned short* __restrict__ Wup,   // [256,128] bf16
        const unsigned short* __restrict__ Wd,    // [3,256,256] bf16
        const float* __restrict__ bd,             // [3,256]
        const int* __restrict__ gids,             // [M] sorted
        float* __restrict__ out, int M) {
    __shared__ char Abuf[32768];
    __shared__ char Wbuf[32768];
    const int t    = threadIdx.x;
    const int w    = t >> 6;
    const int lane = t & 63;
    const int r    = lane & 15;
    const int g    = lane >> 4;
    const int row0 = blockIdx.x * 64;

    f32x4 acc[4][4];

    // ---- stage A0: 64 rows x 256B (pre-swizzled source, linear dest) ----
#pragma unroll
    for (int it = 0; it < 4; ++it) {
        int unit = it * 256 + t;
        int row  = unit >> 4;
        int seg  = unit & 15;
        int csrc = (seg * 16) ^ ((row & 7) << 4);
        int ga = row0 + row; if (ga >= M) ga = M - 1;
        gload_lds16((const char*)A0 + (size_t)ga * 256 + csrc, Abuf + unit * 16);
    }

    // ---- layer 0: K=128 ----
#pragma unroll
    for (int i = 0; i < 4; ++i)
#pragma unroll
        for (int j = 0; j < 4; ++j) acc[i][j] = (f32x4){0.f, 0.f, 0.f, 0.f};
#pragma unroll
    for (int kci = 0; kci < 2; ++kci) {
        const int kc = kci * 64;
        if (kci) __syncthreads();
#pragma unroll
        for (int it = 0; it < 8; ++it) {
            int unit = it * 256 + t;
            int wrow = unit >> 3;
            int seg  = unit & 7;
            int csrc = (seg * 16) ^ ((wrow & 7) << 4);
            gload_lds16((const char*)Wup + (size_t)wrow * 256 + kc * 2 + csrc,
                        Wbuf + unit * 16);
        }
        asm volatile("s_waitcnt vmcnt(0)" ::: "memory");
        __syncthreads();
#pragma unroll
        for (int ks = 0; ks < 2; ++ks) {
            short8 af[4], bf[4];
#pragma unroll
            for (int mi = 0; mi < 4; ++mi) {
                int row = mi * 16 + r;
                int off = kc * 2 + ks * 64 + g * 16;
                af[mi] = *(const short8*)(Abuf + row * 256 + (off ^ ((row & 7) << 4)));
            }
#pragma unroll
            for (int nj = 0; nj < 4; ++nj) {
                int col = w * 64 + nj * 16 + r;
                bf[nj] = *(const short8*)(Wbuf + col * 128
                          + ((ks * 64 + g * 16) ^ ((col & 7) << 4)));
            }
#pragma unroll
            for (int mi = 0; mi < 4; ++mi)
#pragma unroll
                for (int nj = 0; nj < 4; ++nj)
                    acc[mi][nj] = __builtin_amdgcn_mfma_f32_16x16x32_bf16(
                        af[mi], bf[nj], acc[mi][nj], 0, 0, 0);
        }
    }
    __syncthreads();
#pragma unroll
    for (int mi = 0; mi < 4; ++mi)
#pragma unroll
        for (int nj = 0; nj < 4; ++nj)
#pragma unroll
            for (int q = 0; q < 4; ++q) {
                int row = mi * 16 + g * 4 + q;
                int col = w * 64 + nj * 16 + r;
                *(unsigned short*)(Abuf + row * 512 + ((col * 2) ^ ((row & 7) << 4)))
                    = f32_to_bf16(acc[mi][nj][q]);
            }
    __syncthreads();

    // ---- layers 1..3: K=256 ----
    for (int ell = 0; ell < NDENSE; ++ell) {
        const unsigned short* Wl = Wd + (size_t)ell * OUT * OUT;
        const float* bias = bd + ell * OUT;
#pragma unroll
        for (int i = 0; i < 4; ++i)
#pragma unroll
            for (int j = 0; j < 4; ++j) acc[i][j] = (f32x4){0.f, 0.f, 0.f, 0.f};
#pragma unroll
        for (int kci = 0; kci < 4; ++kci) {
            const int kc = kci * 64;
            __syncthreads();
#pragma unroll
            for (int it = 0; it < 8; ++it) {
                int unit = it * 256 + t;
                int wrow = unit >> 3;
                int seg  = unit & 7;
                int csrc = (seg * 16) ^ ((wrow & 7) << 4);
                gload_lds16((const char*)Wl + (size_t)wrow * 512 + kc * 2 + csrc,
                            Wbuf + unit * 16);
            }
            asm volatile("s_waitcnt vmcnt(0)" ::: "memory");
            __syncthreads();
#pragma unroll
            for (int ks = 0; ks < 2; ++ks) {
                short8 af[4], bf[4];
#pragma unroll
                for (int mi = 0; mi < 4; ++mi) {
                    int row = mi * 16 + r;
                    int off = kc * 2 + ks * 64 + g * 16;
                    af[mi] = *(const short8*)(Abuf + row * 512 + (off ^ ((row & 7) << 4)));
                }
#pragma unroll
                for (int nj = 0; nj < 4; ++nj) {
                    int col = w * 64 + nj * 16 + r;
                    bf[nj] = *(const short8*)(Wbuf + col * 128
                              + ((ks * 64 + g * 16) ^ ((col & 7) << 4)));
                }
#pragma unroll
                for (int mi = 0; mi < 4; ++mi)
#pragma unroll
                    for (int nj = 0; nj < 4; ++nj)
                        acc[mi][nj] = __builtin_amdgcn_mfma_f32_16x16x32_bf16(
                            af[mi], bf[nj], acc[mi][nj], 0, 0, 0);
            }
        }
        __syncthreads();
        if (ell < NDENSE - 1) {
#pragma unroll
            for (int mi = 0; mi < 4; ++mi)
#pragma unroll
                for (int nj = 0; nj < 4; ++nj) {
                    int col = w * 64 + nj * 16 + r;
                    float b = bias[col];
#pragma unroll
                    for (int q = 0; q < 4; ++q) {
                        int row = mi * 16 + g * 4 + q;
                        *(unsigned short*)(Abuf + row * 512
                            + ((col * 2) ^ ((row & 7) << 4)))
                            = f32_to_bf16(silu(acc[mi][nj][q] + b));
                    }
                }
            __syncthreads();
        } else {
            // ---- final layer: silu + per-graph reduce, atomicAdd into out ----
            bool uni = (row0 + 63 < M) && (gids[row0] == gids[row0 + 63]);
            if (uni) {
                int gph = gids[row0];
                float* og = out + (size_t)gph * OUT;
#pragma unroll
                for (int nj = 0; nj < 4; ++nj) {
                    int gcol = w * 64 + nj * 16 + r;
                    float b = bias[gcol];
                    float s = 0.f;
#pragma unroll
                    for (int mi = 0; mi < 4; ++mi)
#pragma unroll
                        for (int q = 0; q < 4; ++q)
                            s += silu(acc[mi][nj][q] + b);
                    s += __shfl_xor(s, 16);
                    s += __shfl_xor(s, 32);
                    if (g == 0) atomicAdd(&og[gcol], s);
                }
            } else {
#pragma unroll
                for (int nj = 0; nj < 4; ++nj) {
                    int gcol = w * 64 + nj * 16 + r;
                    float b = bias[gcol];
#pragma unroll
                    for (int mi = 0; mi < 4; ++mi)
#pragma unroll
                        for (int q = 0; q < 4; ++q) {
                            int grow = row0 + mi * 16 + g * 4 + q;
                            if (grow < M)
                                atomicAdd(&out[(size_t)gids[grow] * OUT + gcol],
                                          silu(acc[mi][nj][q] + b));
                        }
                }
            }
        }
    }
}

// ---------- host ----------
extern "C" void kernel_launch(void* const* d_in, const int* in_sizes, int n_in,
                              void* d_out, int out_size, void* d_ws, size_t ws_size,
                              hipStream_t stream) {
    const float* m         = (const float*)d_in[0];
    const float* rbf       = (const float*)d_in[1];
    const int*   src       = (const int*)d_in[2];
    const int*   gids      = (const int*)d_in[3];
    const float* W_rbf     = (const float*)d_in[4];
    const float* W_up      = (const float*)d_in[5];
    const float* W_dense   = (const float*)d_in[6];
    const float* b_dense   = (const float*)d_in[7];
    float* out = (float*)d_out;

    const int E = in_sizes[2];
    const int N = in_sizes[3];
    const int nbkt = (N + 127) >> BSH;     // 391 for N=50000

    size_t off = 0;
    auto alloc = [&](size_t bytes) -> void* {
        void* p = (char*)d_ws + off;
        off += (bytes + 255) & ~(size_t)255;
        return p;
    };
    int* bpart   = (int*)alloc((size_t)HB * MAXBKT * 4);
    int* bbase   = (int*)alloc((size_t)(MAXBKT + 1) * 4);
    int* gcursor = (int*)alloc((size_t)MAXBKT * 4);
    int* offsets = (int*)alloc(((size_t)N + 1) * 4);
    int2* pairs  = (int2*)alloc((size_t)E * 8);
    int* perm    = (int*)alloc((size_t)E * 4);
    unsigned short* t_bf = (unsigned short*)alloc((size_t)N * EMB * 2);
    unsigned short* Wbf  = (unsigned short*)alloc((size_t)(OUT * EMB + NDENSE * OUT * OUT) * 2);
    unsigned short* Wup_bf = Wbf;
    unsigned short* Wd_bf  = Wbf + OUT * EMB;

    // K0: setup = hist partials + weight convert + out zero (merged)
    setup_hist_kernel<<<HB, 256, 0, stream>>>(src, bpart, W_up, W_dense, Wbf,
                                              out, E, nbkt, out_size);
    // K1..K3: scan, scatter, local CSR
    bscan_kernel<<<1, MAXBKT, 0, stream>>>(bpart, bbase, gcursor, nbkt, E);
    bscatter_kernel<<<512, 256, 0, stream>>>(src, gcursor, pairs, E, nbkt);
    local_csr_kernel<<<nbkt, 256, 0, stream>>>(pairs, bbase, offsets, perm, N, E, nbkt);

    // edge transform + node gather v4 (32-edge chunks)
    edge_accum_kernel<<<2048, 256, 0, stream>>>(m, rbf, perm, offsets, W_rbf,
                                                (uint2*)t_bf, N);

    // fused MLP + per-graph readout (atomic into zeroed out)
    fused_mlp2_kernel<<<(N + 63) / 64, 256, 0, stream>>>(t_bf, Wup_bf, Wd_bf,
                                                         b_dense, gids, out, N);
}